// Round 5
// baseline (1953.992 us; speedup 1.0000x reference)
//
#include <hip/hip_runtime.h>
#include <hip/hip_fp16.h>

#define NN 100000
#define NE 1600000
#define CHUNK 1024
#define NCHUNK ((NN + CHUNK - 1) / CHUNK)

// ---------------- preprocessing ----------------

__global__ void count_kernel(const int* __restrict__ dst, int* __restrict__ cnt) {
    int e = blockIdx.x * blockDim.x + threadIdx.x;
    if (e < NE) atomicAdd(&cnt[dst[e]], 1);
}

// dis[i] = rsqrt(deg_i+1);  xs = dis-prescaled x rows (for aggx)
__global__ void dis_xs_kernel(const int* __restrict__ cnt, const float* __restrict__ x,
                              float* __restrict__ dis, float* __restrict__ xs) {
    int i = blockIdx.x * blockDim.x + threadIdx.x;
    if (i >= NN) return;
    float d = rsqrtf((float)(cnt[i] + 1));
    dis[i] = d;
    xs[i * 3 + 0] = d * x[i * 3 + 0];
    xs[i * 3 + 1] = d * x[i * 3 + 1];
    xs[i * 3 + 2] = d * x[i * 3 + 2];
}

// hierarchical exclusive scan of (cnt[i]+1)  [self-loop included in CSR]
__global__ __launch_bounds__(256) void scan1_kernel(const int* __restrict__ cnt,
                                                    int* __restrict__ row_ptr,
                                                    int* __restrict__ sums) {
    __shared__ int sdata[256];
    const int b = blockIdx.x, t = threadIdx.x;
    const int base = b * CHUNK + t * 4;
    int v0 = (base + 0 < NN) ? cnt[base + 0] + 1 : 0;
    int v1 = (base + 1 < NN) ? cnt[base + 1] + 1 : 0;
    int v2 = (base + 2 < NN) ? cnt[base + 2] + 1 : 0;
    int v3 = (base + 3 < NN) ? cnt[base + 3] + 1 : 0;
    const int s = v0 + v1 + v2 + v3;
    sdata[t] = s;
    __syncthreads();
    for (int off = 1; off < 256; off <<= 1) {
        int xv = (t >= off) ? sdata[t - off] : 0;
        __syncthreads();
        sdata[t] += xv;
        __syncthreads();
    }
    const int excl = sdata[t] - s;
    if (base + 0 < NN) row_ptr[base + 0] = excl;
    if (base + 1 < NN) row_ptr[base + 1] = excl + v0;
    if (base + 2 < NN) row_ptr[base + 2] = excl + v0 + v1;
    if (base + 3 < NN) row_ptr[base + 3] = excl + v0 + v1 + v2;
    if (t == 255) sums[b] = sdata[255];
}

__global__ __launch_bounds__(128) void scan2_kernel(int* __restrict__ sums,
                                                    int* __restrict__ row_ptr) {
    __shared__ int sd[128];
    const int t = threadIdx.x;
    const int v = (t < NCHUNK) ? sums[t] : 0;
    sd[t] = v;
    __syncthreads();
    for (int off = 1; off < 128; off <<= 1) {
        int xv = (t >= off) ? sd[t - off] : 0;
        __syncthreads();
        sd[t] += xv;
        __syncthreads();
    }
    if (t < NCHUNK) sums[t] = sd[t] - v;
    if (t == 127) row_ptr[NN] = sd[127];
}

__global__ void scan3_kernel(int* __restrict__ row_ptr, const int* __restrict__ sums) {
    int i = blockIdx.x * blockDim.x + threadIdx.x;
    if (i < NN) row_ptr[i] += sums[i >> 10];
}

// CSR fill: col only (1 edge/thread: max TLP for the atomic->store chain)
__global__ void fill_kernel(const int* __restrict__ src, const int* __restrict__ dst,
                            const int* __restrict__ row_ptr, int* __restrict__ fil,
                            int* __restrict__ col) {
    int e = blockIdx.x * blockDim.x + threadIdx.x;
    if (e >= NE) return;
    int d = dst[e];
    int pos = atomicAdd(&fil[d], 1);
    col[row_ptr[d] + pos] = src[e];
}

__global__ void selffill_kernel(const int* __restrict__ row_ptr, const int* __restrict__ cnt,
                                int* __restrict__ col) {
    int i = blockIdx.x * blockDim.x + threadIdx.x;
    if (i >= NN) return;
    col[row_ptr[i] + cnt[i]] = i;  // self edge last in the row
}

// ax = Ahat @ x = dis_i * sum_j xs[j]   (CSR includes self loop)
__global__ void aggx_kernel(const float* __restrict__ xs, const int* __restrict__ row_ptr,
                            const int* __restrict__ col, const float* __restrict__ dis,
                            float* __restrict__ ax) {
    int i = blockIdx.x * blockDim.x + threadIdx.x;
    if (i >= NN) return;
    float a0 = 0.f, a1 = 0.f, a2 = 0.f;
    int e = row_ptr[i + 1];
    for (int p = row_ptr[i]; p < e; ++p) {
        int j = col[p];
        a0 += xs[j * 3 + 0];
        a1 += xs[j * 3 + 1];
        a2 += xs[j * 3 + 2];
    }
    float d = dis[i];
    ax[i * 3 + 0] = d * a0; ax[i * 3 + 1] = d * a1; ax[i * 3 + 2] = d * a2;
}

// t16 = fp16(dis * relu(ax @ Wp + bp));  xr = ax @ Wr[64:67,:] + br
__global__ void proj_kernel(const float* __restrict__ ax,
                            const float* __restrict__ Wp, const float* __restrict__ bp,
                            const float* __restrict__ Wr, const float* __restrict__ br,
                            const float* __restrict__ dis,
                            __half* __restrict__ t16, float* __restrict__ xr) {
    int g = blockIdx.x * blockDim.x + threadIdx.x;
    if (g >= NN * 64) return;
    int i = g >> 6, c = g & 63;
    float a0 = ax[i * 3 + 0], a1 = ax[i * 3 + 1], a2 = ax[i * 3 + 2];
    float tp = fmaxf(a0 * Wp[c] + a1 * Wp[64 + c] + a2 * Wp[128 + c] + bp[c], 0.f);
    t16[g] = __float2half(tp * dis[i]);
    xr[g] = a0 * Wr[64 * 64 + c] + a1 * Wr[65 * 64 + c] + a2 * Wr[66 * 64 + c] + br[c];
}

// ---------------- fused GCN ----------------
// h16 rows fp16, pre-scaled by dis[j]. agg_i = dis_i * sum_{j in row} h16[j].
// Tile = 64 rows; the tile's CSR edge span is CONTIGUOUS -> stage all column
// indices into LDS with one coalesced copy, so phase-1 gathers depend only on
// LDS index reads (no global colv->gather latency chain). Uniform-branch
// fallback to global colv if the tile has > ECAP edges (statistically never).

__device__ __forceinline__ void acc8_fma(float* a, float m, uint4 r) {
    union { uint4 u; __half2 h[4]; } cv;
    cv.u = r;
#pragma unroll
    for (int t = 0; t < 4; ++t) {
        float2 f = __half22float2(cv.h[t]);
        a[2 * t]     = fmaf(m, f.x, a[2 * t]);
        a[2 * t + 1] = fmaf(m, f.y, a[2 * t + 1]);
    }
}

template <int IN_W, int OUT_W, bool RELU, bool HAS_ADD, bool HAS_BIAS, bool W32, bool W16>
__global__ __launch_bounds__(256, 6) void gcn_kernel(
    const __half* __restrict__ h16, const float* __restrict__ Wg,
    const float* __restrict__ bias, const float* __restrict__ addsrc,
    const int* __restrict__ row_ptr, const int* __restrict__ colv,
    const float* __restrict__ dis,
    float* __restrict__ out32, __half* __restrict__ out16) {
    constexpr int TILE_R = 64;
    constexpr int ECAP = 2048;           // mean tile edges ~1088, sigma ~33
    constexpr int QUADS = IN_W / 8;      // lanes per row (16B = 8 halves each)
    constexpr int SLOTS = 64 / QUADS;    // rows gathered per wave instruction
    constexpr int STR = IN_W + 4;
    __shared__ __align__(16) float aggT[TILE_R][STR];
    __shared__ int eidx[ECAP];
    __shared__ int rp[TILE_R + 1];
    __shared__ float rdis[TILE_R];

    const int tid = threadIdx.x;
    const int tile0 = blockIdx.x * TILE_R;

    if (tid <= TILE_R) rp[tid] = row_ptr[min(tile0 + tid, NN)];
    if (tid < TILE_R) {
        const int i = tile0 + tid;
        rdis[tid] = (i < NN) ? dis[i] : 0.f;
    }
    __syncthreads();
    const int E0 = rp[0];
    const int E1 = rp[TILE_R];
    const int ecount = E1 - E0;
    const bool fits = (ecount <= ECAP);
    if (fits) {
        for (int k = tid; k < ecount; k += 256) eidx[k] = colv[E0 + k];
    }
    __syncthreads();

    const int wave = tid >> 6;
    const int lane = tid & 63;
    const int fq = lane & (QUADS - 1);
    const int slot = lane / QUADS;

    auto phase1 = [&](auto fetch) {
        for (int rr = 0; rr < 16; ++rr) {
            const int rl = (wave << 4) + rr;
            const int s = rp[rl] - E0;
            const int e = rp[rl + 1] - E0;
            const int last = e - 1;          // every row has >= 1 edge (self loop)
            float a0[8], a1[8];
#pragma unroll
            for (int t = 0; t < 8; ++t) { a0[t] = 0.f; a1[t] = 0.f; }
            for (int p0 = s + slot; p0 < e; p0 += 2 * SLOTS) {
                const int p1 = p0 + SLOTS;
                const float m1 = (p1 < e) ? 1.f : 0.f;
                const int j0 = fetch(p0);
                const int j1 = fetch(min(p1, last));
                const uint4 g0 = *(const uint4*)(h16 + (size_t)j0 * IN_W + (fq << 3));
                const uint4 g1 = *(const uint4*)(h16 + (size_t)j1 * IN_W + (fq << 3));
                acc8_fma(a0, 1.f, g0);
                acc8_fma(a1, m1, g1);
            }
            float acc[8];
#pragma unroll
            for (int t = 0; t < 8; ++t) acc[t] = a0[t] + a1[t];
#pragma unroll
            for (int m = QUADS; m < 64; m <<= 1) {
#pragma unroll
                for (int t = 0; t < 8; ++t) acc[t] += __shfl_xor(acc[t], m, 64);
            }
            if (slot == 0) {
                const float d = rdis[rl];
#pragma unroll
                for (int t = 0; t < 8; ++t) acc[t] *= d;
                *(float4*)&aggT[rl][(fq << 3)]     = make_float4(acc[0], acc[1], acc[2], acc[3]);
                *(float4*)&aggT[rl][(fq << 3) + 4] = make_float4(acc[4], acc[5], acc[6], acc[7]);
            }
        }
    };
    if (fits) {
        phase1([&](int p) { return eidx[p]; });
    } else {
        phase1([&](int p) { return colv[E0 + p]; });
    }
    __syncthreads();

    // phase 2: [64 x IN_W] fp32 @ [IN_W x OUT_W], W from global (L1-resident)
    constexpr int CPT = (OUT_W >= 4) ? 4 : OUT_W;
    constexpr int TXN = OUT_W / CPT;
    const int tx = tid % TXN;
    const int ty = tid / TXN;
    if (ty < TILE_R / 4) {
        float c[4][CPT];
#pragma unroll
        for (int r = 0; r < 4; ++r)
#pragma unroll
            for (int q = 0; q < CPT; ++q) c[r][q] = 0.f;

#pragma unroll 2
        for (int k4 = 0; k4 < IN_W / 4; ++k4) {
            float4 av[4];
#pragma unroll
            for (int r = 0; r < 4; ++r) av[r] = *(const float4*)&aggT[ty * 4 + r][k4 << 2];
#pragma unroll
            for (int kk = 0; kk < 4; ++kk) {
                float wv[CPT];
                if constexpr (CPT == 4) {
                    const float4 w4 = *(const float4*)(Wg + ((k4 << 2) + kk) * OUT_W + (tx << 2));
                    wv[0] = w4.x; wv[1] = w4.y; wv[2] = w4.z; wv[3] = w4.w;
                } else {
#pragma unroll
                    for (int q = 0; q < CPT; ++q)
                        wv[q] = Wg[((k4 << 2) + kk) * OUT_W + tx * CPT + q];
                }
#pragma unroll
                for (int r = 0; r < 4; ++r) {
                    const float ar = ((const float*)&av[r])[kk];
#pragma unroll
                    for (int q = 0; q < CPT; ++q) c[r][q] += ar * wv[q];
                }
            }
        }
        float bq[CPT];
#pragma unroll
        for (int q = 0; q < CPT; ++q) bq[q] = HAS_BIAS ? bias[tx * CPT + q] : 0.f;
#pragma unroll
        for (int r = 0; r < 4; ++r) {
            const int i = tile0 + ty * 4 + r;
            if (i < NN) {
                float o[CPT];
#pragma unroll
                for (int q = 0; q < CPT; ++q) o[q] = c[r][q] + bq[q];
                if constexpr (HAS_ADD) {
#pragma unroll
                    for (int q = 0; q < CPT; ++q) o[q] += addsrc[i * OUT_W + tx * CPT + q];
                }
                if constexpr (RELU) {
#pragma unroll
                    for (int q = 0; q < CPT; ++q) o[q] = fmaxf(o[q], 0.f);
                }
                if constexpr (W32) {
                    if constexpr (CPT == 4) {
                        *(float4*)(out32 + i * OUT_W + (tx << 2)) =
                            make_float4(o[0], o[1], o[2], o[3]);
                    } else {
#pragma unroll
                        for (int q = 0; q < CPT; ++q) out32[i * OUT_W + tx * CPT + q] = o[q];
                    }
                }
                if constexpr (W16) {
                    const float d = dis[i];
                    if constexpr (CPT == 4) {
                        union { uint2 u; __half2 h[2]; } pk;
                        pk.h[0] = __float22half2_rn(make_float2(o[0] * d, o[1] * d));
                        pk.h[1] = __float22half2_rn(make_float2(o[2] * d, o[3] * d));
                        *(uint2*)(out16 + i * OUT_W + (tx << 2)) = pk.u;
                    } else {
#pragma unroll
                        for (int q = 0; q < CPT; ++q)
                            out16[i * OUT_W + tx * CPT + q] = __float2half(o[q] * d);
                    }
                }
            }
        }
    }
}

// ---------------- driver ----------------

extern "C" void kernel_launch(void* const* d_in, const int* in_sizes, int n_in,
                              void* d_out, int out_size, void* d_ws, size_t ws_size,
                              hipStream_t stream) {
    const float* x   = (const float*)d_in[0];
    const float* Wp  = (const float*)d_in[1];
    const float* bp  = (const float*)d_in[2];
    const float* Wr  = (const float*)d_in[3];
    const float* br  = (const float*)d_in[4];
    const float* W11 = (const float*)d_in[5];
    const float* b11 = (const float*)d_in[6];
    const float* W12 = (const float*)d_in[7];
    const float* b12 = (const float*)d_in[8];
    const float* W21 = (const float*)d_in[9];
    const float* b21 = (const float*)d_in[10];
    const float* W22 = (const float*)d_in[11];
    const float* b22 = (const float*)d_in[12];
    const float* Wh1 = (const float*)d_in[13];
    const float* bh1 = (const float*)d_in[14];
    const float* Wh2 = (const float*)d_in[15];
    const float* bh2 = (const float*)d_in[16];
    const float* Wh3 = (const float*)d_in[17];
    const float* bh3 = (const float*)d_in[18];
    const int* edge  = (const int*)d_in[19];
    const int* srcA = edge;
    const int* dstA = edge + NE;
    float* outp = (float*)d_out;

    char* p = (char*)d_ws;
    auto carve = [&](size_t bytes) {
        char* r = p;
        p += (bytes + 255) & ~(size_t)255;
        return r;
    };
    int*    cnt  = (int*)carve(NN * 4);
    int*    fil  = (int*)carve(NN * 4);
    int*    rptr = (int*)carve((NN + 1) * 4);
    float*  dis  = (float*)carve(NN * 4);
    int*    sums = (int*)carve(128 * 4);
    int*    colv = (int*)carve((size_t)(NE + NN + 256) * 4);
    float*  xs   = (float*)carve((size_t)NN * 3 * 4);
    float*  ax   = (float*)carve((size_t)NN * 3 * 4);
    float*  xr   = (float*)carve((size_t)NN * 64 * 4);
    float*  bu32 = (float*)carve((size_t)NN * 64 * 4);
    float*  bw32 = (float*)carve((size_t)NN * 64 * 4);
    __half* bt16 = (__half*)carve((size_t)NN * 64 * 2);
    __half* bu16 = (__half*)carve((size_t)NN * 64 * 2);
    __half* bv16 = (__half*)carve((size_t)NN * 64 * 2);
    __half* bw16 = (__half*)carve((size_t)NN * 64 * 2);

    hipMemsetAsync(cnt, 0, NN * 4, stream);
    hipMemsetAsync(fil, 0, NN * 4, stream);
    count_kernel<<<(NE + 255) / 256, 256, 0, stream>>>(dstA, cnt);
    dis_xs_kernel<<<(NN + 255) / 256, 256, 0, stream>>>(cnt, x, dis, xs);
    scan1_kernel<<<NCHUNK, 256, 0, stream>>>(cnt, rptr, sums);
    scan2_kernel<<<1, 128, 0, stream>>>(sums, rptr);
    scan3_kernel<<<(NN + 255) / 256, 256, 0, stream>>>(rptr, sums);
    fill_kernel<<<(NE + 255) / 256, 256, 0, stream>>>(srcA, dstA, rptr, fil, colv);
    selffill_kernel<<<(NN + 255) / 256, 256, 0, stream>>>(rptr, cnt, colv);
    aggx_kernel<<<(NN + 255) / 256, 256, 0, stream>>>(xs, rptr, colv, dis, ax);
    proj_kernel<<<(NN * 64 + 255) / 256, 256, 0, stream>>>(ax, Wp, bp, Wr, br, dis, bt16, xr);

    const int GB = (NN + 63) / 64;
    for (int it = 0; it < 5; ++it) {
        gcn_kernel<64, 64, false, true, false, true, true><<<GB, 256, 0, stream>>>(
            bt16, Wr, nullptr, xr, rptr, colv, dis, bu32, bu16);
        gcn_kernel<64, 64, true, false, true, false, true><<<GB, 256, 0, stream>>>(
            bu16, W11, b11, nullptr, rptr, colv, dis, nullptr, bv16);
        gcn_kernel<64, 64, true, true, true, true, true><<<GB, 256, 0, stream>>>(
            bv16, W12, b12, bu32, rptr, colv, dis, bw32, bw16);
        gcn_kernel<64, 64, true, false, true, false, true><<<GB, 256, 0, stream>>>(
            bw16, W21, b21, nullptr, rptr, colv, dis, nullptr, bv16);
        gcn_kernel<64, 64, true, true, true, false, true><<<GB, 256, 0, stream>>>(
            bv16, W22, b22, bw32, rptr, colv, dis, nullptr, bt16);
    }
    gcn_kernel<64, 32, true, false, true, false, true><<<GB, 256, 0, stream>>>(
        bt16, Wh1, bh1, nullptr, rptr, colv, dis, nullptr, bv16);
    gcn_kernel<32, 8, true, false, true, false, true><<<GB, 256, 0, stream>>>(
        bv16, Wh2, bh2, nullptr, rptr, colv, dis, nullptr, bw16);
    gcn_kernel<8, 2, false, false, true, true, false><<<GB, 256, 0, stream>>>(
        bw16, Wh3, bh3, nullptr, rptr, colv, dis, outp, nullptr);
}

// Round 6
// 1757.909 us; speedup vs baseline: 1.1115x; 1.1115x over previous
//
#include <hip/hip_runtime.h>
#include <hip/hip_fp16.h>

#define NN 100000
#define NE 1600000
#define CHUNK 1024
#define NCHUNK ((NN + CHUNK - 1) / CHUNK)

// ---------------- preprocessing ----------------

__global__ void count_kernel(const int* __restrict__ dst, int* __restrict__ cnt) {
    int e = blockIdx.x * blockDim.x + threadIdx.x;
    if (e < NE) atomicAdd(&cnt[dst[e]], 1);
}

// dis[i] = rsqrt(deg_i+1);  xs = dis-prescaled x rows (for aggx)
__global__ void dis_xs_kernel(const int* __restrict__ cnt, const float* __restrict__ x,
                              float* __restrict__ dis, float* __restrict__ xs) {
    int i = blockIdx.x * blockDim.x + threadIdx.x;
    if (i >= NN) return;
    float d = rsqrtf((float)(cnt[i] + 1));
    dis[i] = d;
    xs[i * 3 + 0] = d * x[i * 3 + 0];
    xs[i * 3 + 1] = d * x[i * 3 + 1];
    xs[i * 3 + 2] = d * x[i * 3 + 2];
}

// hierarchical exclusive scan of (cnt[i]+1)  [self-loop included in CSR]
__global__ __launch_bounds__(256) void scan1_kernel(const int* __restrict__ cnt,
                                                    int* __restrict__ row_ptr,
                                                    int* __restrict__ sums) {
    __shared__ int sdata[256];
    const int b = blockIdx.x, t = threadIdx.x;
    const int base = b * CHUNK + t * 4;
    int v0 = (base + 0 < NN) ? cnt[base + 0] + 1 : 0;
    int v1 = (base + 1 < NN) ? cnt[base + 1] + 1 : 0;
    int v2 = (base + 2 < NN) ? cnt[base + 2] + 1 : 0;
    int v3 = (base + 3 < NN) ? cnt[base + 3] + 1 : 0;
    const int s = v0 + v1 + v2 + v3;
    sdata[t] = s;
    __syncthreads();
    for (int off = 1; off < 256; off <<= 1) {
        int xv = (t >= off) ? sdata[t - off] : 0;
        __syncthreads();
        sdata[t] += xv;
        __syncthreads();
    }
    const int excl = sdata[t] - s;
    if (base + 0 < NN) row_ptr[base + 0] = excl;
    if (base + 1 < NN) row_ptr[base + 1] = excl + v0;
    if (base + 2 < NN) row_ptr[base + 2] = excl + v0 + v1;
    if (base + 3 < NN) row_ptr[base + 3] = excl + v0 + v1 + v2;
    if (t == 255) sums[b] = sdata[255];
}

__global__ __launch_bounds__(128) void scan2_kernel(int* __restrict__ sums,
                                                    int* __restrict__ row_ptr) {
    __shared__ int sd[128];
    const int t = threadIdx.x;
    const int v = (t < NCHUNK) ? sums[t] : 0;
    sd[t] = v;
    __syncthreads();
    for (int off = 1; off < 128; off <<= 1) {
        int xv = (t >= off) ? sd[t - off] : 0;
        __syncthreads();
        sd[t] += xv;
        __syncthreads();
    }
    if (t < NCHUNK) sums[t] = sd[t] - v;
    if (t == 127) row_ptr[NN] = sd[127];
}

__global__ void scan3_kernel(int* __restrict__ row_ptr, const int* __restrict__ sums) {
    int i = blockIdx.x * blockDim.x + threadIdx.x;
    if (i < NN) row_ptr[i] += sums[i >> 10];
}

// CSR fill: col only (1 edge/thread: max TLP for the atomic->store chain)
__global__ void fill_kernel(const int* __restrict__ src, const int* __restrict__ dst,
                            const int* __restrict__ row_ptr, int* __restrict__ fil,
                            int* __restrict__ col) {
    int e = blockIdx.x * blockDim.x + threadIdx.x;
    if (e >= NE) return;
    int d = dst[e];
    int pos = atomicAdd(&fil[d], 1);
    col[row_ptr[d] + pos] = src[e];
}

__global__ void selffill_kernel(const int* __restrict__ row_ptr, const int* __restrict__ cnt,
                                int* __restrict__ col) {
    int i = blockIdx.x * blockDim.x + threadIdx.x;
    if (i >= NN) return;
    col[row_ptr[i] + cnt[i]] = i;  // self edge last in the row
}

// ax = Ahat @ x = dis_i * sum_j xs[j]   (CSR includes self loop)
__global__ void aggx_kernel(const float* __restrict__ xs, const int* __restrict__ row_ptr,
                            const int* __restrict__ col, const float* __restrict__ dis,
                            float* __restrict__ ax) {
    int i = blockIdx.x * blockDim.x + threadIdx.x;
    if (i >= NN) return;
    float a0 = 0.f, a1 = 0.f, a2 = 0.f;
    int e = row_ptr[i + 1];
    for (int p = row_ptr[i]; p < e; ++p) {
        int j = col[p];
        a0 += xs[j * 3 + 0];
        a1 += xs[j * 3 + 1];
        a2 += xs[j * 3 + 2];
    }
    float d = dis[i];
    ax[i * 3 + 0] = d * a0; ax[i * 3 + 1] = d * a1; ax[i * 3 + 2] = d * a2;
}

// t16 = fp16(dis * relu(ax @ Wp + bp));  xr = ax @ Wr[64:67,:] + br
__global__ void proj_kernel(const float* __restrict__ ax,
                            const float* __restrict__ Wp, const float* __restrict__ bp,
                            const float* __restrict__ Wr, const float* __restrict__ br,
                            const float* __restrict__ dis,
                            __half* __restrict__ t16, float* __restrict__ xr) {
    int g = blockIdx.x * blockDim.x + threadIdx.x;
    if (g >= NN * 64) return;
    int i = g >> 6, c = g & 63;
    float a0 = ax[i * 3 + 0], a1 = ax[i * 3 + 1], a2 = ax[i * 3 + 2];
    float tp = fmaxf(a0 * Wp[c] + a1 * Wp[64 + c] + a2 * Wp[128 + c] + bp[c], 0.f);
    t16[g] = __float2half(tp * dis[i]);
    xr[g] = a0 * Wr[64 * 64 + c] + a1 * Wr[65 * 64 + c] + a2 * Wr[66 * 64 + c] + br[c];
}

// ---------------- fused GCN ----------------
// h16 rows fp16, pre-scaled by dis[j]. agg_i = dis_i * sum_{j in row} h16[j].
// Phase 1: lane = (slot, fq). STRAIGHT-LINE body of 4 masked clamped gathers
// per row (covers deg <= 4*SLOTS; Poisson(16) => tail loop ~never taken).
// No back-edge => all 4 gathers issue before any use; masked lanes clamp to
// the row's self-edge (same address -> L1 broadcast, ~no extra traffic).
// Phase 2: [64 x IN_W] fp32 @ [IN_W x OUT_W], W from global (L1-resident).
// __launch_bounds__(256,8): 8 blocks/CU (LDS ~17.9KB*8=143KB), 32 waves/CU.

__device__ __forceinline__ void acc8_fma(float* a, float m, uint4 r) {
    union { uint4 u; __half2 h[4]; } cv;
    cv.u = r;
#pragma unroll
    for (int t = 0; t < 4; ++t) {
        float2 f = __half22float2(cv.h[t]);
        a[2 * t]     = fmaf(m, f.x, a[2 * t]);
        a[2 * t + 1] = fmaf(m, f.y, a[2 * t + 1]);
    }
}

template <int IN_W, int OUT_W, bool RELU, bool HAS_ADD, bool HAS_BIAS, bool W32, bool W16>
__global__ __launch_bounds__(256, 8) void gcn_kernel(
    const __half* __restrict__ h16, const float* __restrict__ Wg,
    const float* __restrict__ bias, const float* __restrict__ addsrc,
    const int* __restrict__ row_ptr, const int* __restrict__ colv,
    const float* __restrict__ dis,
    float* __restrict__ out32, __half* __restrict__ out16) {
    constexpr int TILE_R = 64;
    constexpr int QUADS = IN_W / 8;      // lanes per row (16B = 8 halves each)
    constexpr int SLOTS = 64 / QUADS;    // rows gathered per wave instruction
    constexpr int STR = IN_W + 4;
    __shared__ __align__(16) float aggT[TILE_R][STR];
    __shared__ int rp[TILE_R + 1];
    __shared__ float rdis[TILE_R];

    const int tid = threadIdx.x;
    const int tile0 = blockIdx.x * TILE_R;

    if (tid <= TILE_R) rp[tid] = row_ptr[min(tile0 + tid, NN)];
    if (tid < TILE_R) {
        const int i = tile0 + tid;
        rdis[tid] = (i < NN) ? dis[i] : 0.f;
    }
    __syncthreads();

    const int wave = tid >> 6;
    const int lane = tid & 63;
    const int fq = lane & (QUADS - 1);
    const int slot = lane / QUADS;

    for (int rr = 0; rr < 16; ++rr) {
        const int rl = (wave << 4) + rr;
        const int s = __builtin_amdgcn_readfirstlane(rp[rl]);
        const int e = __builtin_amdgcn_readfirstlane(rp[rl + 1]);
        const int last = e - 1;              // every row has >= 1 edge (self loop)
        float a01[8], a23[8];
#pragma unroll
        for (int t = 0; t < 8; ++t) { a01[t] = 0.f; a23[t] = 0.f; }

        // straight-line: 4 masked clamped gathers (deg <= 4*SLOTS covered)
        {
            const int p0 = s + slot;
            const int p1 = p0 + SLOTS;
            const int p2 = p0 + 2 * SLOTS;
            const int p3 = p0 + 3 * SLOTS;
            const float m0 = (p0 < e) ? 1.f : 0.f;
            const float m1 = (p1 < e) ? 1.f : 0.f;
            const float m2 = (p2 < e) ? 1.f : 0.f;
            const float m3 = (p3 < e) ? 1.f : 0.f;
            const int j0 = colv[min(p0, last)];
            const int j1 = colv[min(p1, last)];
            const int j2 = colv[min(p2, last)];
            const int j3 = colv[min(p3, last)];
            const uint4 g0 = *(const uint4*)(h16 + (size_t)j0 * IN_W + (fq << 3));
            const uint4 g1 = *(const uint4*)(h16 + (size_t)j1 * IN_W + (fq << 3));
            const uint4 g2 = *(const uint4*)(h16 + (size_t)j2 * IN_W + (fq << 3));
            const uint4 g3 = *(const uint4*)(h16 + (size_t)j3 * IN_W + (fq << 3));
            acc8_fma(a01, m0, g0);
            acc8_fma(a01, m1, g1);
            acc8_fma(a23, m2, g2);
            acc8_fma(a23, m3, g3);
        }
        // rare tail (deg > 4*SLOTS): wave-uniform branch
        if (e - s > 4 * SLOTS) {
            for (int p = s + 4 * SLOTS + slot; p < e; p += SLOTS) {
                const int j = colv[p];
                const uint4 g = *(const uint4*)(h16 + (size_t)j * IN_W + (fq << 3));
                acc8_fma(a01, 1.f, g);
            }
        }
        float acc[8];
#pragma unroll
        for (int t = 0; t < 8; ++t) acc[t] = a01[t] + a23[t];
#pragma unroll
        for (int m = QUADS; m < 64; m <<= 1) {
#pragma unroll
            for (int t = 0; t < 8; ++t) acc[t] += __shfl_xor(acc[t], m, 64);
        }
        if (slot == 0) {
            const float d = rdis[rl];
#pragma unroll
            for (int t = 0; t < 8; ++t) acc[t] *= d;
            *(float4*)&aggT[rl][(fq << 3)]     = make_float4(acc[0], acc[1], acc[2], acc[3]);
            *(float4*)&aggT[rl][(fq << 3) + 4] = make_float4(acc[4], acc[5], acc[6], acc[7]);
        }
    }
    __syncthreads();

    // phase 2: [64 x IN_W] fp32 @ [IN_W x OUT_W], W from global (L1-resident)
    constexpr int CPT = (OUT_W >= 4) ? 4 : OUT_W;
    constexpr int TXN = OUT_W / CPT;
    const int tx = tid % TXN;
    const int ty = tid / TXN;
    if (ty < TILE_R / 4) {
        float c[4][CPT];
#pragma unroll
        for (int r = 0; r < 4; ++r)
#pragma unroll
            for (int q = 0; q < CPT; ++q) c[r][q] = 0.f;

#pragma unroll 2
        for (int k4 = 0; k4 < IN_W / 4; ++k4) {
            float4 av[4];
#pragma unroll
            for (int r = 0; r < 4; ++r) av[r] = *(const float4*)&aggT[ty * 4 + r][k4 << 2];
#pragma unroll
            for (int kk = 0; kk < 4; ++kk) {
                float wv[CPT];
                if constexpr (CPT == 4) {
                    const float4 w4 = *(const float4*)(Wg + ((k4 << 2) + kk) * OUT_W + (tx << 2));
                    wv[0] = w4.x; wv[1] = w4.y; wv[2] = w4.z; wv[3] = w4.w;
                } else {
#pragma unroll
                    for (int q = 0; q < CPT; ++q)
                        wv[q] = Wg[((k4 << 2) + kk) * OUT_W + tx * CPT + q];
                }
#pragma unroll
                for (int r = 0; r < 4; ++r) {
                    const float ar = ((const float*)&av[r])[kk];
#pragma unroll
                    for (int q = 0; q < CPT; ++q) c[r][q] += ar * wv[q];
                }
            }
        }
        float bq[CPT];
#pragma unroll
        for (int q = 0; q < CPT; ++q) bq[q] = HAS_BIAS ? bias[tx * CPT + q] : 0.f;
#pragma unroll
        for (int r = 0; r < 4; ++r) {
            const int i = tile0 + ty * 4 + r;
            if (i < NN) {
                float o[CPT];
#pragma unroll
                for (int q = 0; q < CPT; ++q) o[q] = c[r][q] + bq[q];
                if constexpr (HAS_ADD) {
#pragma unroll
                    for (int q = 0; q < CPT; ++q) o[q] += addsrc[i * OUT_W + tx * CPT + q];
                }
                if constexpr (RELU) {
#pragma unroll
                    for (int q = 0; q < CPT; ++q) o[q] = fmaxf(o[q], 0.f);
                }
                if constexpr (W32) {
                    if constexpr (CPT == 4) {
                        *(float4*)(out32 + i * OUT_W + (tx << 2)) =
                            make_float4(o[0], o[1], o[2], o[3]);
                    } else {
#pragma unroll
                        for (int q = 0; q < CPT; ++q) out32[i * OUT_W + tx * CPT + q] = o[q];
                    }
                }
                if constexpr (W16) {
                    const float d = dis[i];
                    if constexpr (CPT == 4) {
                        union { uint2 u; __half2 h[2]; } pk;
                        pk.h[0] = __float22half2_rn(make_float2(o[0] * d, o[1] * d));
                        pk.h[1] = __float22half2_rn(make_float2(o[2] * d, o[3] * d));
                        *(uint2*)(out16 + i * OUT_W + (tx << 2)) = pk.u;
                    } else {
#pragma unroll
                        for (int q = 0; q < CPT; ++q)
                            out16[i * OUT_W + tx * CPT + q] = __float2half(o[q] * d);
                    }
                }
            }
        }
    }
}

// ---------------- driver ----------------

extern "C" void kernel_launch(void* const* d_in, const int* in_sizes, int n_in,
                              void* d_out, int out_size, void* d_ws, size_t ws_size,
                              hipStream_t stream) {
    const float* x   = (const float*)d_in[0];
    const float* Wp  = (const float*)d_in[1];
    const float* bp  = (const float*)d_in[2];
    const float* Wr  = (const float*)d_in[3];
    const float* br  = (const float*)d_in[4];
    const float* W11 = (const float*)d_in[5];
    const float* b11 = (const float*)d_in[6];
    const float* W12 = (const float*)d_in[7];
    const float* b12 = (const float*)d_in[8];
    const float* W21 = (const float*)d_in[9];
    const float* b21 = (const float*)d_in[10];
    const float* W22 = (const float*)d_in[11];
    const float* b22 = (const float*)d_in[12];
    const float* Wh1 = (const float*)d_in[13];
    const float* bh1 = (const float*)d_in[14];
    const float* Wh2 = (const float*)d_in[15];
    const float* bh2 = (const float*)d_in[16];
    const float* Wh3 = (const float*)d_in[17];
    const float* bh3 = (const float*)d_in[18];
    const int* edge  = (const int*)d_in[19];
    const int* srcA = edge;
    const int* dstA = edge + NE;
    float* outp = (float*)d_out;

    char* p = (char*)d_ws;
    auto carve = [&](size_t bytes) {
        char* r = p;
        p += (bytes + 255) & ~(size_t)255;
        return r;
    };
    int*    cnt  = (int*)carve(NN * 4);
    int*    fil  = (int*)carve(NN * 4);
    int*    rptr = (int*)carve((NN + 1) * 4);
    float*  dis  = (float*)carve(NN * 4);
    int*    sums = (int*)carve(128 * 4);
    int*    colv = (int*)carve((size_t)(NE + NN + 256) * 4);
    float*  xs   = (float*)carve((size_t)NN * 3 * 4);
    float*  ax   = (float*)carve((size_t)NN * 3 * 4);
    float*  xr   = (float*)carve((size_t)NN * 64 * 4);
    float*  bu32 = (float*)carve((size_t)NN * 64 * 4);
    float*  bw32 = (float*)carve((size_t)NN * 64 * 4);
    __half* bt16 = (__half*)carve((size_t)NN * 64 * 2);
    __half* bu16 = (__half*)carve((size_t)NN * 64 * 2);
    __half* bv16 = (__half*)carve((size_t)NN * 64 * 2);
    __half* bw16 = (__half*)carve((size_t)NN * 64 * 2);

    hipMemsetAsync(cnt, 0, NN * 4, stream);
    hipMemsetAsync(fil, 0, NN * 4, stream);
    count_kernel<<<(NE + 255) / 256, 256, 0, stream>>>(dstA, cnt);
    dis_xs_kernel<<<(NN + 255) / 256, 256, 0, stream>>>(cnt, x, dis, xs);
    scan1_kernel<<<NCHUNK, 256, 0, stream>>>(cnt, rptr, sums);
    scan2_kernel<<<1, 128, 0, stream>>>(sums, rptr);
    scan3_kernel<<<(NN + 255) / 256, 256, 0, stream>>>(rptr, sums);
    fill_kernel<<<(NE + 255) / 256, 256, 0, stream>>>(srcA, dstA, rptr, fil, colv);
    selffill_kernel<<<(NN + 255) / 256, 256, 0, stream>>>(rptr, cnt, colv);
    aggx_kernel<<<(NN + 255) / 256, 256, 0, stream>>>(xs, rptr, colv, dis, ax);
    proj_kernel<<<(NN * 64 + 255) / 256, 256, 0, stream>>>(ax, Wp, bp, Wr, br, dis, bt16, xr);

    const int GB = (NN + 63) / 64;
    for (int it = 0; it < 5; ++it) {
        gcn_kernel<64, 64, false, true, false, true, true><<<GB, 256, 0, stream>>>(
            bt16, Wr, nullptr, xr, rptr, colv, dis, bu32, bu16);
        gcn_kernel<64, 64, true, false, true, false, true><<<GB, 256, 0, stream>>>(
            bu16, W11, b11, nullptr, rptr, colv, dis, nullptr, bv16);
        gcn_kernel<64, 64, true, true, true, true, true><<<GB, 256, 0, stream>>>(
            bv16, W12, b12, bu32, rptr, colv, dis, bw32, bw16);
        gcn_kernel<64, 64, true, false, true, false, true><<<GB, 256, 0, stream>>>(
            bw16, W21, b21, nullptr, rptr, colv, dis, nullptr, bv16);
        gcn_kernel<64, 64, true, true, true, false, true><<<GB, 256, 0, stream>>>(
            bv16, W22, b22, bw32, rptr, colv, dis, nullptr, bt16);
    }
    gcn_kernel<64, 32, true, false, true, false, true><<<GB, 256, 0, stream>>>(
        bt16, Wh1, bh1, nullptr, rptr, colv, dis, nullptr, bv16);
    gcn_kernel<32, 8, true, false, true, false, true><<<GB, 256, 0, stream>>>(
        bv16, Wh2, bh2, nullptr, rptr, colv, dis, nullptr, bw16);
    gcn_kernel<8, 2, false, false, true, true, false><<<GB, 256, 0, stream>>>(
        bw16, Wh3, bh3, nullptr, rptr, colv, dis, outp, nullptr);
}